// Round 1
// baseline (633.800 us; speedup 1.0000x reference)
//
#include <hip/hip_runtime.h>
#include <hip/hip_bf16.h>

// Problem constants
#define DIMV   1024
#define HEADSV 16
#define DHEADV 64
#define WIDTHV 512
#define INNERV 1024
#define BATCHV 2
#define SEQV   4096
#define NROWS  (BATCHV*SEQV)       // 8192
#define KVROWS (WIDTHV + SEQV)     // 4608 = 512 xl prefix + 4096

typedef short bf16x8 __attribute__((ext_vector_type(8)));
typedef float f32x4  __attribute__((ext_vector_type(4)));

static __device__ __forceinline__ short f2bf(float f) {
  __hip_bfloat16 h = __float2bfloat16(f);
  return __builtin_bit_cast(short, h);
}
static __device__ __forceinline__ float bf2f(short s) {
  unsigned u = ((unsigned)(unsigned short)s) << 16;
  return __builtin_bit_cast(float, u);
}

// ---------------------------------------------------------------- LayerNorm
__global__ __launch_bounds__(256) void ln_kernel(const float* __restrict__ x,
                                                 const float* __restrict__ gamma,
                                                 short* __restrict__ xn) {
  int row = blockIdx.x;                    // 8192 rows
  int t = threadIdx.x;                     // 256 threads, 4 floats each
  const float* xr = x + (size_t)row * DIMV;
  float4 v = reinterpret_cast<const float4*>(xr)[t];
  float s  = v.x + v.y + v.z + v.w;
  float sq = v.x*v.x + v.y*v.y + v.z*v.z + v.w*v.w;
  #pragma unroll
  for (int o = 32; o > 0; o >>= 1) { s += __shfl_down(s, o); sq += __shfl_down(sq, o); }
  __shared__ float red[8];
  int wv = t >> 6;
  if ((t & 63) == 0) { red[wv] = s; red[4 + wv] = sq; }
  __syncthreads();
  s  = red[0] + red[1] + red[2] + red[3];
  sq = red[4] + red[5] + red[6] + red[7];
  float mean = s * (1.0f/1024.0f);
  float var  = sq * (1.0f/1024.0f) - mean*mean;
  float rstd = rsqrtf(var + 1e-5f);
  float4 g = reinterpret_cast<const float4*>(gamma)[t];
  short4 o4;
  o4.x = f2bf((v.x - mean) * rstd * g.x);
  o4.y = f2bf((v.y - mean) * rstd * g.y);
  o4.z = f2bf((v.z - mean) * rstd * g.z);
  o4.w = f2bf((v.w - mean) * rstd * g.w);
  reinterpret_cast<short4*>(xn + (size_t)row * DIMV)[t] = o4;
}

// -------------------------------------- transpose fp32 (R,C) -> bf16 (C,R)
__global__ __launch_bounds__(256) void transpose_f32_bf16(const float* __restrict__ in,
                                                          short* __restrict__ out,
                                                          int R, int C) {
  __shared__ float tile[32][33];
  int tc = blockIdx.x * 32;   // col tile in input
  int tr = blockIdx.y * 32;   // row tile in input
  int tx = threadIdx.x & 31, ty = threadIdx.x >> 5;   // ty 0..7
  #pragma unroll
  for (int i = 0; i < 32; i += 8)
    tile[ty + i][tx] = in[(size_t)(tr + ty + i) * C + tc + tx];
  __syncthreads();
  #pragma unroll
  for (int i = 0; i < 32; i += 8)
    out[(size_t)(tc + ty + i) * R + tr + tx] = f2bf(tile[tx][ty + i]);
}

// ---------------------------------------------------- fp32 -> bf16 convert
__global__ void convert_bf16(const float* __restrict__ in, short* __restrict__ out) {
  size_t i = ((size_t)blockIdx.x * 256 + threadIdx.x) * 4;
  float4 v = *reinterpret_cast<const float4*>(in + i);
  short4 o; o.x = f2bf(v.x); o.y = f2bf(v.y); o.z = f2bf(v.z); o.w = f2bf(v.w);
  *reinterpret_cast<short4*>(out + i) = o;
}

// --------------------------- xl_memories (2,B,H,512,64) -> k_all/v_all head
__global__ void xl_to_kv(const float* __restrict__ xl,
                         short* __restrict__ k_all, short* __restrict__ v_all) {
  int tid = blockIdx.x * 256 + threadIdx.x;      // 524288 threads, 4 elems each
  int d = (tid & 15) * 4;
  int rest = tid >> 4;
  int s = rest & 511; rest >>= 9;
  int h = rest & 15;  rest >>= 4;
  int b = rest & 1;   int m2 = rest >> 1;
  float4 v = *reinterpret_cast<const float4*>(
      xl + ((((size_t)((m2*2 + b)*16 + h))*512 + s)*64 + d));
  short4 o; o.x = f2bf(v.x); o.y = f2bf(v.y); o.z = f2bf(v.z); o.w = f2bf(v.w);
  short* dst = (m2 ? v_all : k_all) + (((size_t)(b*16 + h)*KVROWS + s)*64 + d);
  *reinterpret_cast<short4*>(dst) = o;
}

// -------------------- v_all (32,4608,64) -> vt (32,64,4608), XOR-swizzled LDS
__global__ __launch_bounds__(256) void transpose_v(const short* __restrict__ v,
                                                   short* __restrict__ vt) {
  __shared__ __align__(16) short tile[64][72];   // 9 chunks of 8; chunk 8 = pad
  int bh = blockIdx.y;                // 32
  int s0 = blockIdx.x * 64;           // 72 tiles along kv rows
  int tid = threadIdx.x;
  const short* src = v + (size_t)bh * KVROWS * 64;
  #pragma unroll
  for (int p = 0; p < 2; ++p) {
    int flat = p*256 + tid;           // 0..511
    int row = flat >> 3, ch = flat & 7;
    int pch = ch ^ (row >> 3);        // swizzle chunk by s-high-bits
    *reinterpret_cast<int4*>(&tile[row][pch*8]) =
      *reinterpret_cast<const int4*>(src + (size_t)(s0 + row)*64 + ch*8);
  }
  __syncthreads();
  short* dst = vt + (size_t)bh * 64 * KVROWS;
  #pragma unroll
  for (int p = 0; p < 2; ++p) {
    int flat = p*256 + tid;
    int d = flat >> 3, sch = flat & 7;
    short tmp[8];
    #pragma unroll
    for (int k = 0; k < 8; ++k) {
      int s = sch*8 + k;
      int pch = (d >> 3) ^ (s >> 3);
      tmp[k] = tile[s][pch*8 + (d & 7)];
    }
    *reinterpret_cast<int4*>(dst + (size_t)d*KVROWS + s0 + sch*8) =
      *reinterpret_cast<const int4*>(tmp);
  }
}

// ------------------------------------------------------------- MFMA GEMM
// C[M=8192, N] = A[8192,1024] @ B^T  (B stored (N,1024) bf16, both row-major)
// MODE 0: N=3072, scatter q/k_all/v_all (bf16) + memories (fp32, last window)
// MODE 1: N=1024, plain fp32 output
template<int MODE>
__global__ __launch_bounds__(256) void gemm_bt(
    const short* __restrict__ A, const short* __restrict__ Bm,
    short* __restrict__ qo, short* __restrict__ ko, short* __restrict__ vo,
    float* __restrict__ memo, float* __restrict__ co, int N) {
  __shared__ __align__(16) short As[128*40];
  __shared__ __align__(16) short Bs[128*40];
  const int K = 1024;
  int bm = blockIdx.x * 128;
  int bn = blockIdx.y * 128;
  int tid = threadIdx.x;
  int lane = tid & 63, wid = tid >> 6;
  int wr = wid >> 1, wc = wid & 1;
  int fr = lane & 15, fq = lane >> 4;

  f32x4 acc[4][4] = {};

  for (int k0 = 0; k0 < K; k0 += 32) {
    #pragma unroll
    for (int p = 0; p < 2; ++p) {
      int flat = p*256 + tid;
      int row = flat >> 2, ch = flat & 3;
      *reinterpret_cast<int4*>(&As[row*40 + ch*8]) =
        *reinterpret_cast<const int4*>(&A[(size_t)(bm + row)*K + k0 + ch*8]);
      *reinterpret_cast<int4*>(&Bs[row*40 + ch*8]) =
        *reinterpret_cast<const int4*>(&Bm[(size_t)(bn + row)*K + k0 + ch*8]);
    }
    __syncthreads();
    bf16x8 af[4], bfr[4];
    #pragma unroll
    for (int i = 0; i < 4; ++i) {
      af[i]  = *reinterpret_cast<const bf16x8*>(&As[(wr*64 + i*16 + fr)*40 + fq*8]);
      bfr[i] = *reinterpret_cast<const bf16x8*>(&Bs[(wc*64 + i*16 + fr)*40 + fq*8]);
    }
    #pragma unroll
    for (int i = 0; i < 4; ++i)
      #pragma unroll
      for (int j = 0; j < 4; ++j)
        acc[i][j] = __builtin_amdgcn_mfma_f32_16x16x32_bf16(af[i], bfr[j], acc[i][j], 0, 0, 0);
    __syncthreads();
  }

  if (MODE == 0) {
    #pragma unroll
    for (int i = 0; i < 4; ++i)
      #pragma unroll
      for (int j = 0; j < 4; ++j)
        #pragma unroll
        for (int r = 0; r < 4; ++r) {
          int m = bm + wr*64 + i*16 + fq*4 + r;
          int n = bn + wc*64 + j*16 + fr;
          float val = acc[i][j][r];
          int b = m >> 12, s = m & 4095;
          if (n < 1024) {
            qo[(size_t)m*1024 + n] = f2bf(val);
          } else {
            int h = (n >> 6) & 15, d = n & 63;
            size_t idx = ((size_t)((b << 4) + h)*KVROWS + 512 + s)*64 + d;
            if (n < 2048) ko[idx] = f2bf(val);
            else          vo[idx] = f2bf(val);
            if (s >= 3584) {   // last window -> memories output, fp32
              int m2 = (n < 2048) ? 0 : 1;
              memo[((size_t)(((m2*2 + b) << 4) + h)*512 + (s - 3584))*64 + d] = val;
            }
          }
        }
  } else {
    #pragma unroll
    for (int i = 0; i < 4; ++i)
      #pragma unroll
      for (int j = 0; j < 4; ++j)
        #pragma unroll
        for (int r = 0; r < 4; ++r) {
          int m = bm + wr*64 + i*16 + fq*4 + r;
          int n = bn + wc*64 + j*16 + fr;
          co[(size_t)m*N + n] = acc[i][j][r];
        }
  }
}

// ------------------------------------------------------- flash attention
// grid 256 = (b,w,h) with h fastest (XCD L2 locality on bias slices).
// 8 waves x 64 q-rows; per-wave causal tile count; no block-wide barriers.
__global__ __launch_bounds__(512) void attn_kernel(
    const short* __restrict__ q,      // (8192, 1024)
    const short* __restrict__ k_all,  // (32, 4608, 64)
    const short* __restrict__ vt,     // (32, 64, 4608)
    const short* __restrict__ biasb,  // (16, 512, 1024) bf16
    short* __restrict__ attnb) {      // (8192, 1024)
  __shared__ __align__(16) short P[8][2][16*72];  // per-wave double-buffered P

  int bid = blockIdx.x;
  int h  = bid & 15;
  int bw = bid >> 4;
  int b  = bw >> 3, w = bw & 7;
  int lane = threadIdx.x & 63, wid = threadIdx.x >> 6;
  int fr = lane & 15, fq = lane >> 4;
  int qbase = wid * 64;

  const short* qrow = q + ((size_t)(b*SEQV + w*WIDTHV + qbase))*1024 + h*64;
  bf16x8 qf[4][2];
  #pragma unroll
  for (int i = 0; i < 4; ++i)
    #pragma unroll
    for (int c = 0; c < 2; ++c)
      qf[i][c] = *reinterpret_cast<const bf16x8*>(qrow + (size_t)(i*16 + fr)*1024 + c*32 + fq*8);

  f32x4 o[4][4] = {};
  float mrow[4][4], lrow[4][4];
  #pragma unroll
  for (int i = 0; i < 4; ++i)
    #pragma unroll
    for (int r = 0; r < 4; ++r) { mrow[i][r] = -1e30f; lrow[i][r] = 0.f; }

  const short* kbase = k_all + (size_t)(b*16 + h)*KVROWS*64 + (size_t)w*512*64;
  const short* vbase = vt    + (size_t)(b*16 + h)*64*KVROWS + (size_t)w*512;
  const short* bbase = biasb + (size_t)h*512*1024;

  int tmax = wid + 8;                 // last (diagonal) tile for this wave
  for (int t = 0; t <= tmax; ++t) {
    int j0 = t*64;
    f32x4 s[4][4] = {};
    #pragma unroll
    for (int kc = 0; kc < 2; ++kc) {
      bf16x8 kf[4];
      #pragma unroll
      for (int jc = 0; jc < 4; ++jc)
        kf[jc] = *reinterpret_cast<const bf16x8*>(
            kbase + (size_t)(j0 + jc*16 + fr)*64 + kc*32 + fq*8);
      #pragma unroll
      for (int i = 0; i < 4; ++i)
        #pragma unroll
        for (int jc = 0; jc < 4; ++jc)
          s[i][jc] = __builtin_amdgcn_mfma_f32_16x16x32_bf16(qf[i][kc], kf[jc], s[i][jc], 0, 0, 0);
    }
    bf16x8 vf[2][4];
    #pragma unroll
    for (int jk = 0; jk < 2; ++jk)
      #pragma unroll
      for (int dc = 0; dc < 4; ++dc)
        vf[jk][dc] = *reinterpret_cast<const bf16x8*>(
            vbase + (size_t)(dc*16 + fr)*KVROWS + j0 + jk*32 + fq*8);

    #pragma unroll
    for (int i = 0; i < 4; ++i) {
      #pragma unroll
      for (int jc = 0; jc < 4; ++jc) {
        int jcol = j0 + jc*16 + fr;
        #pragma unroll
        for (int r = 0; r < 4; ++r) {
          int irow = qbase + i*16 + fq*4 + r;
          float bv = bf2f(bbase[(size_t)irow*1024 + jcol]);
          float val = s[i][jc][r]*0.125f + bv;
          s[i][jc][r] = (jcol > irow + 512) ? -1e30f : val;
        }
      }
      float tm[4];
      #pragma unroll
      for (int r = 0; r < 4; ++r)
        tm[r] = fmaxf(fmaxf(s[i][0][r], s[i][1][r]), fmaxf(s[i][2][r], s[i][3][r]));
      #pragma unroll
      for (int off = 1; off < 16; off <<= 1)
        #pragma unroll
        for (int r = 0; r < 4; ++r)
          tm[r] = fmaxf(tm[r], __shfl_xor(tm[r], off));
      float alpha[4];
      #pragma unroll
      for (int r = 0; r < 4; ++r) {
        float mn = fmaxf(mrow[i][r], tm[r]);
        alpha[r] = __expf(mrow[i][r] - mn);
        mrow[i][r] = mn;
      }
      float rsum[4] = {0.f, 0.f, 0.f, 0.f};
      short* Pw = &P[wid][i & 1][0];
      #pragma unroll
      for (int jc = 0; jc < 4; ++jc)
        #pragma unroll
        for (int r = 0; r < 4; ++r) {
          float p = __expf(s[i][jc][r] - mrow[i][r]);
          rsum[r] += p;
          Pw[(fq*4 + r)*72 + jc*16 + fr] = f2bf(p);
        }
      #pragma unroll
      for (int off = 1; off < 16; off <<= 1)
        #pragma unroll
        for (int r = 0; r < 4; ++r)
          rsum[r] += __shfl_xor(rsum[r], off);
      #pragma unroll
      for (int r = 0; r < 4; ++r)
        lrow[i][r] = lrow[i][r]*alpha[r] + rsum[r];
      #pragma unroll
      for (int dc = 0; dc < 4; ++dc)
        #pragma unroll
        for (int r = 0; r < 4; ++r)
          o[i][dc][r] *= alpha[r];
      asm volatile("s_waitcnt lgkmcnt(0)" ::: "memory");  // P visible cross-lane
      #pragma unroll
      for (int jk = 0; jk < 2; ++jk) {
        bf16x8 pf = *reinterpret_cast<const bf16x8*>(&Pw[fr*72 + jk*32 + fq*8]);
        #pragma unroll
        for (int dc = 0; dc < 4; ++dc)
          o[i][dc] = __builtin_amdgcn_mfma_f32_16x16x32_bf16(pf, vf[jk][dc], o[i][dc], 0, 0, 0);
      }
    }
  }
  short* obase = attnb + ((size_t)(b*SEQV + w*WIDTHV + qbase))*1024 + h*64;
  #pragma unroll
  for (int i = 0; i < 4; ++i)
    #pragma unroll
    for (int dc = 0; dc < 4; ++dc)
      #pragma unroll
      for (int r = 0; r < 4; ++r)
        obase[(size_t)(i*16 + fq*4 + r)*1024 + dc*16 + fr] = f2bf(o[i][dc][r] / lrow[i][r]);
}

// ------------------------------------------------------------------- host
extern "C" void kernel_launch(void* const* d_in, const int* in_sizes, int n_in,
                              void* d_out, int out_size, void* d_ws, size_t ws_size,
                              hipStream_t stream) {
  const float* x     = (const float*)d_in[0];
  const float* bias  = (const float*)d_in[1];
  const float* xl    = (const float*)d_in[2];
  const float* gamma = (const float*)d_in[3];
  const float* w_qkv = (const float*)d_in[4];
  const float* w_out = (const float*)d_in[5];
  float* out = (float*)d_out;
  float* mem_out = out + (size_t)BATCHV*SEQV*DIMV;   // +8388608

  char* ws = (char*)d_ws;
  size_t off = 0;
  auto alloc = [&](size_t bytes) { size_t o = off; off += (bytes + 255) & ~(size_t)255; return o; };
  short* xn    = (short*)(ws + alloc((size_t)NROWS*DIMV*2));          // aliased by attnb
  short* wqkvT = (short*)(ws + alloc((size_t)3*INNERV*DIMV*2));
  short* woutT = (short*)(ws + alloc((size_t)DIMV*INNERV*2));
  short* biasb = (short*)(ws + alloc((size_t)HEADSV*WIDTHV*2*WIDTHV*2));
  short* qbuf  = (short*)(ws + alloc((size_t)NROWS*INNERV*2));
  short* k_all = (short*)(ws + alloc((size_t)BATCHV*HEADSV*KVROWS*DHEADV*2));
  short* v_all = (short*)(ws + alloc((size_t)BATCHV*HEADSV*KVROWS*DHEADV*2));
  short* vt    = (short*)(ws + alloc((size_t)BATCHV*HEADSV*KVROWS*DHEADV*2));
  short* attnb = xn;  // xn dead after QKV GEMM; reuse for attention output

  // weight transposes (fp32 (R,C) -> bf16 (C,R))
  transpose_f32_bf16<<<dim3(3*INNERV/32, DIMV/32), 256, 0, stream>>>(w_qkv, wqkvT, DIMV, 3*INNERV);
  transpose_f32_bf16<<<dim3(INNERV/32, DIMV/32), 256, 0, stream>>>(w_out, woutT, DIMV, INNERV);
  // bias -> bf16
  convert_bf16<<<(HEADSV*WIDTHV*2*WIDTHV)/1024, 256, 0, stream>>>(bias, biasb);
  // xl memories -> k_all/v_all prefix rows
  xl_to_kv<<<2048, 256, 0, stream>>>(xl, k_all, v_all);
  // layernorm
  ln_kernel<<<NROWS, 256, 0, stream>>>(x, gamma, xn);
  // QKV projection (+ memories fp32 epilogue)
  gemm_bt<0><<<dim3(NROWS/128, (3*INNERV)/128), 256, 0, stream>>>(
      xn, wqkvT, qbuf, k_all, v_all, mem_out, nullptr, 3*INNERV);
  // V transpose for PV-operand reads
  transpose_v<<<dim3(KVROWS/64, BATCHV*HEADSV), 256, 0, stream>>>(v_all, vt);
  // attention
  attn_kernel<<<BATCHV*8*HEADSV, 512, 0, stream>>>(qbuf, k_all, vt, biasb, attnb);
  // output projection -> fp32 d_out
  gemm_bt<1><<<dim3(NROWS/128, INNERV/128), 256, 0, stream>>>(
      attnb, woutT, nullptr, nullptr, nullptr, nullptr, out, INNERV);
}

// Round 2
// 307.056 us; speedup vs baseline: 2.0641x; 2.0641x over previous
//
#include <hip/hip_runtime.h>
#include <hip/hip_bf16.h>

// Problem constants
#define DIMV   1024
#define HEADSV 16
#define DHEADV 64
#define WIDTHV 512
#define INNERV 1024
#define BATCHV 2
#define SEQV   4096
#define NROWS  (BATCHV*SEQV)       // 8192
#define KVROWS (WIDTHV + SEQV)     // 4608 = 512 xl prefix + 4096

typedef short bf16x8 __attribute__((ext_vector_type(8)));
typedef short bf16x4 __attribute__((ext_vector_type(4)));
typedef int   int4v  __attribute__((ext_vector_type(4)));
typedef float f32x4  __attribute__((ext_vector_type(4)));

static __device__ __forceinline__ short f2bf(float f) {
  __hip_bfloat16 h = __float2bfloat16(f);
  return __builtin_bit_cast(short, h);
}
static __device__ __forceinline__ float bf2f(short s) {
  unsigned u = ((unsigned)(unsigned short)s) << 16;
  return __builtin_bit_cast(float, u);
}
static __device__ __forceinline__ bf16x8 ntload8(const short* p) {
  int4v v = __builtin_nontemporal_load((const int4v*)p);
  return __builtin_bit_cast(bf16x8, v);
}

// ---------------------------------------------------------------- LayerNorm
__global__ __launch_bounds__(256) void ln_kernel(const float* __restrict__ x,
                                                 const float* __restrict__ gamma,
                                                 short* __restrict__ xn) {
  int row = blockIdx.x;                    // 8192 rows
  int t = threadIdx.x;                     // 256 threads, 4 floats each
  const float* xr = x + (size_t)row * DIMV;
  float4 v = reinterpret_cast<const float4*>(xr)[t];
  float s  = v.x + v.y + v.z + v.w;
  float sq = v.x*v.x + v.y*v.y + v.z*v.z + v.w*v.w;
  #pragma unroll
  for (int o = 32; o > 0; o >>= 1) { s += __shfl_down(s, o); sq += __shfl_down(sq, o); }
  __shared__ float red[8];
  int wv = t >> 6;
  if ((t & 63) == 0) { red[wv] = s; red[4 + wv] = sq; }
  __syncthreads();
  s  = red[0] + red[1] + red[2] + red[3];
  sq = red[4] + red[5] + red[6] + red[7];
  float mean = s * (1.0f/1024.0f);
  float var  = sq * (1.0f/1024.0f) - mean*mean;
  float rstd = rsqrtf(var + 1e-5f);
  float4 g = reinterpret_cast<const float4*>(gamma)[t];
  short4 o4;
  o4.x = f2bf((v.x - mean) * rstd * g.x);
  o4.y = f2bf((v.y - mean) * rstd * g.y);
  o4.z = f2bf((v.z - mean) * rstd * g.z);
  o4.w = f2bf((v.w - mean) * rstd * g.w);
  reinterpret_cast<short4*>(xn + (size_t)row * DIMV)[t] = o4;
}

// -------------------------------------- transpose fp32 (R,C) -> bf16 (C,R)
__global__ __launch_bounds__(256) void transpose_f32_bf16(const float* __restrict__ in,
                                                          short* __restrict__ out,
                                                          int R, int C) {
  __shared__ float tile[32][33];
  int tc = blockIdx.x * 32;   // col tile in input
  int tr = blockIdx.y * 32;   // row tile in input
  int tx = threadIdx.x & 31, ty = threadIdx.x >> 5;   // ty 0..7
  #pragma unroll
  for (int i = 0; i < 32; i += 8)
    tile[ty + i][tx] = in[(size_t)(tr + ty + i) * C + tc + tx];
  __syncthreads();
  #pragma unroll
  for (int i = 0; i < 32; i += 8)
    out[(size_t)(tc + ty + i) * R + tr + tx] = f2bf(tile[tx][ty + i]);
}

// ---------------- bias (16,512,1024) fp32 -> fragment-packed bf16
// bp[h][irow>>2][jcol][r] = bias[h][(irow>>2)*4 + r][jcol]
__global__ __launch_bounds__(256) void pack_bias(const float* __restrict__ in,
                                                 short* __restrict__ out) {
  int idx = blockIdx.x * 256 + threadIdx.x;     // 2,097,152 threads
  int j   = idx & 1023;
  int ir4 = (idx >> 10) & 127;
  int h   = idx >> 17;
  const float* src = in + ((size_t)(h*512 + ir4*4))*1024 + j;
  short4 o;
  o.x = f2bf(src[0]);
  o.y = f2bf(src[1024]);
  o.z = f2bf(src[2048]);
  o.w = f2bf(src[3072]);
  *reinterpret_cast<short4*>(out + (size_t)idx*4) = o;
}

// --------------------------- xl_memories (2,B,H,512,64) -> k_all/v_all head
__global__ void xl_to_kv(const float* __restrict__ xl,
                         short* __restrict__ k_all, short* __restrict__ v_all) {
  int tid = blockIdx.x * 256 + threadIdx.x;      // 524288 threads, 4 elems each
  int d = (tid & 15) * 4;
  int rest = tid >> 4;
  int s = rest & 511; rest >>= 9;
  int h = rest & 15;  rest >>= 4;
  int b = rest & 1;   int m2 = rest >> 1;
  float4 v = *reinterpret_cast<const float4*>(
      xl + ((((size_t)((m2*2 + b)*16 + h))*512 + s)*64 + d));
  short4 o; o.x = f2bf(v.x); o.y = f2bf(v.y); o.z = f2bf(v.z); o.w = f2bf(v.w);
  short* dst = (m2 ? v_all : k_all) + (((size_t)(b*16 + h)*KVROWS + s)*64 + d);
  *reinterpret_cast<short4*>(dst) = o;
}

// -------------------- v_all (32,4608,64) -> vt (32,64,4608), XOR-swizzled LDS
__global__ __launch_bounds__(256) void transpose_v(const short* __restrict__ v,
                                                   short* __restrict__ vt) {
  __shared__ __align__(16) short tile[64][72];   // 9 chunks of 8; chunk 8 = pad
  int bh = blockIdx.y;                // 32
  int s0 = blockIdx.x * 64;           // 72 tiles along kv rows
  int tid = threadIdx.x;
  const short* src = v + (size_t)bh * KVROWS * 64;
  #pragma unroll
  for (int p = 0; p < 2; ++p) {
    int flat = p*256 + tid;           // 0..511
    int row = flat >> 3, ch = flat & 7;
    int pch = ch ^ (row >> 3);        // swizzle chunk by s-high-bits
    *reinterpret_cast<int4v*>(&tile[row][pch*8]) =
      *reinterpret_cast<const int4v*>(src + (size_t)(s0 + row)*64 + ch*8);
  }
  __syncthreads();
  short* dst = vt + (size_t)bh * 64 * KVROWS;
  #pragma unroll
  for (int p = 0; p < 2; ++p) {
    int flat = p*256 + tid;
    int d = flat >> 3, sch = flat & 7;
    short tmp[8];
    #pragma unroll
    for (int k = 0; k < 8; ++k) {
      int s = sch*8 + k;
      int pch = (d >> 3) ^ (s >> 3);
      tmp[k] = tile[s][pch*8 + (d & 7)];
    }
    *reinterpret_cast<int4v*>(dst + (size_t)d*KVROWS + s0 + sch*8) =
      *reinterpret_cast<const int4v*>(tmp);
  }
}

// ------------------------------------------------------------- MFMA GEMM
// C[M=8192, N] = A[8192,1024] @ B^T  (B stored (N,1024) bf16, both row-major)
// MODE 0: N=3072, scatter q(*0.125)/k_all/v_all (bf16) + memories (fp32)
// MODE 1: N=1024, plain fp32 output
template<int MODE>
__global__ __launch_bounds__(256) void gemm_bt(
    const short* __restrict__ A, const short* __restrict__ Bm,
    short* __restrict__ qo, short* __restrict__ ko, short* __restrict__ vo,
    float* __restrict__ memo, float* __restrict__ co, int N) {
  __shared__ __align__(16) short As[128*40];
  __shared__ __align__(16) short Bs[128*40];
  const int K = 1024;
  int bm = blockIdx.x * 128;
  int bn = blockIdx.y * 128;
  int tid = threadIdx.x;
  int lane = tid & 63, wid = tid >> 6;
  int wr = wid >> 1, wc = wid & 1;
  int fr = lane & 15, fq = lane >> 4;

  f32x4 acc[4][4] = {};

  for (int k0 = 0; k0 < K; k0 += 32) {
    #pragma unroll
    for (int p = 0; p < 2; ++p) {
      int flat = p*256 + tid;
      int row = flat >> 2, ch = flat & 3;
      *reinterpret_cast<int4v*>(&As[row*40 + ch*8]) =
        *reinterpret_cast<const int4v*>(&A[(size_t)(bm + row)*K + k0 + ch*8]);
      *reinterpret_cast<int4v*>(&Bs[row*40 + ch*8]) =
        *reinterpret_cast<const int4v*>(&Bm[(size_t)(bn + row)*K + k0 + ch*8]);
    }
    __syncthreads();
    bf16x8 af[4], bfr[4];
    #pragma unroll
    for (int i = 0; i < 4; ++i) {
      af[i]  = *reinterpret_cast<const bf16x8*>(&As[(wr*64 + i*16 + fr)*40 + fq*8]);
      bfr[i] = *reinterpret_cast<const bf16x8*>(&Bs[(wc*64 + i*16 + fr)*40 + fq*8]);
    }
    #pragma unroll
    for (int i = 0; i < 4; ++i)
      #pragma unroll
      for (int j = 0; j < 4; ++j)
        acc[i][j] = __builtin_amdgcn_mfma_f32_16x16x32_bf16(af[i], bfr[j], acc[i][j], 0, 0, 0);
    __syncthreads();
  }

  if (MODE == 0) {
    #pragma unroll
    for (int i = 0; i < 4; ++i)
      #pragma unroll
      for (int j = 0; j < 4; ++j)
        #pragma unroll
        for (int r = 0; r < 4; ++r) {
          int m = bm + wr*64 + i*16 + fq*4 + r;
          int n = bn + wc*64 + j*16 + fr;
          float val = acc[i][j][r];
          int b = m >> 12, s = m & 4095;
          if (n < 1024) {
            qo[(size_t)m*1024 + n] = f2bf(val * 0.125f);   // fold attn scale into q
          } else {
            int h = (n >> 6) & 15, d = n & 63;
            size_t idx = ((size_t)((b << 4) + h)*KVROWS + 512 + s)*64 + d;
            if (n < 2048) ko[idx] = f2bf(val);
            else          vo[idx] = f2bf(val);
            if (s >= 3584) {   // last window -> memories output, fp32
              int m2 = (n < 2048) ? 0 : 1;
              memo[((size_t)(((m2*2 + b) << 4) + h)*512 + (s - 3584))*64 + d] = val;
            }
          }
        }
  } else {
    #pragma unroll
    for (int i = 0; i < 4; ++i)
      #pragma unroll
      for (int j = 0; j < 4; ++j)
        #pragma unroll
        for (int r = 0; r < 4; ++r) {
          int m = bm + wr*64 + i*16 + fq*4 + r;
          int n = bn + wc*64 + j*16 + fr;
          co[(size_t)m*N + n] = acc[i][j][r];
        }
  }
}

// ------------------------------------------------------- flash attention
// grid 256 = (b,w,h) h-fastest (pins the 2 heads' bias slices per XCD L2).
// 8 waves x 64 q-rows; cooperative double-buffered K/V LDS staging (nt loads);
// bias consumed as MFMA C-init from fragment-packed bf16.
__global__ __launch_bounds__(512) void attn_kernel(
    const short* __restrict__ q,      // (8192, 1024), pre-scaled by 0.125
    const short* __restrict__ k_all,  // (32, 4608, 64)
    const short* __restrict__ vt,     // (32, 64, 4608)
    const short* __restrict__ bp,     // (16,128,1024,4) packed bf16
    short* __restrict__ attnb) {      // (8192, 1024)
  __shared__ __align__(16) short Ks[2][64*72];
  __shared__ __align__(16) short Vs[2][64*72];
  __shared__ __align__(16) short Pb[8][2][16*72];

  const int bid = blockIdx.x;
  const int h = bid & 15, bw = bid >> 4, b = bw >> 3, w = bw & 7;
  const int tid = threadIdx.x, lane = tid & 63, wid = tid >> 6;
  const int fr = lane & 15, fq = lane >> 4;
  const int qbase = wid * 64;

  // Q fragments in registers (read-once -> nontemporal)
  const short* qrow = q + ((size_t)(b*SEQV + w*WIDTHV + qbase))*1024 + h*64;
  bf16x8 qf[4][2];
  #pragma unroll
  for (int i = 0; i < 4; ++i)
    #pragma unroll
    for (int c = 0; c < 2; ++c)
      qf[i][c] = ntload8(qrow + (size_t)(i*16 + fr)*1024 + c*32 + fq*8);

  f32x4 o[4][4] = {};
  float mrow[4][4], lrow[4][4];
  #pragma unroll
  for (int i = 0; i < 4; ++i)
    #pragma unroll
    for (int r = 0; r < 4; ++r) { mrow[i][r] = -1e30f; lrow[i][r] = 0.f; }

  const short* kg  = k_all + ((size_t)(b*16 + h)*KVROWS + w*512)*64;
  const short* vg  = vt    + (size_t)(b*16 + h)*64*KVROWS + w*512;
  const short* bpw = bp    + ((size_t)(h*128 + (qbase >> 2) + fq))*4096;

  // staging coords: 512 threads x 16B = one 64x64 bf16 tile per pass
  const int srow = tid >> 3, sch = tid & 7;
  const short* kgs = kg + (size_t)srow*64 + sch*8;
  const short* vgs = vg + (size_t)srow*KVROWS + sch*8;
  const int soff = srow*72 + sch*8;

  { // prologue: stage tile 0
    int4v kk = __builtin_nontemporal_load((const int4v*)kgs);
    int4v vv = __builtin_nontemporal_load((const int4v*)vgs);
    *reinterpret_cast<int4v*>(&Ks[0][soff]) = kk;
    *reinterpret_cast<int4v*>(&Vs[0][soff]) = vv;
  }
  __syncthreads();

  const int tmax = wid + 8;            // diagonal tile for this wave
  for (int t = 0; t < 16; ++t) {
    const int buf = t & 1;
    int4v kk, vv;
    const bool more = (t < 15);
    if (more) {  // issue next-tile loads early; latency hides under compute
      kk = __builtin_nontemporal_load((const int4v*)(kgs + (size_t)(t+1)*64*64));
      vv = __builtin_nontemporal_load((const int4v*)(vgs + (t+1)*64));
    }
    if (t <= tmax) {
      const int j0 = t * 64;
      // bias fragments (coalesced 8B vector loads, L2-resident slice)
      bf16x4 bb[4][4];
      #pragma unroll
      for (int i = 0; i < 4; ++i)
        #pragma unroll
        for (int jc = 0; jc < 4; ++jc)
          bb[i][jc] = *reinterpret_cast<const bf16x4*>(
              &bpw[(size_t)i*16384 + (size_t)(j0 + jc*16 + fr)*4]);
      bf16x8 kf0[4], kf1[4];
      #pragma unroll
      for (int jc = 0; jc < 4; ++jc) {
        kf0[jc] = *reinterpret_cast<const bf16x8*>(&Ks[buf][(jc*16 + fr)*72 + fq*8]);
        kf1[jc] = *reinterpret_cast<const bf16x8*>(&Ks[buf][(jc*16 + fr)*72 + 32 + fq*8]);
      }
      bf16x8 vf[2][4];
      #pragma unroll
      for (int jk = 0; jk < 2; ++jk)
        #pragma unroll
        for (int dc = 0; dc < 4; ++dc)
          vf[jk][dc] = *reinterpret_cast<const bf16x8*>(
              &Vs[buf][(dc*16 + fr)*72 + jk*32 + fq*8]);

      // QK^T with bias as C-init (scale already folded into q)
      f32x4 s[4][4];
      #pragma unroll
      for (int i = 0; i < 4; ++i)
        #pragma unroll
        for (int jc = 0; jc < 4; ++jc) {
          f32x4 c;
          c[0] = bf2f(bb[i][jc][0]); c[1] = bf2f(bb[i][jc][1]);
          c[2] = bf2f(bb[i][jc][2]); c[3] = bf2f(bb[i][jc][3]);
          s[i][jc] = __builtin_amdgcn_mfma_f32_16x16x32_bf16(qf[i][0], kf0[jc], c, 0, 0, 0);
        }
      #pragma unroll
      for (int i = 0; i < 4; ++i)
        #pragma unroll
        for (int jc = 0; jc < 4; ++jc)
          s[i][jc] = __builtin_amdgcn_mfma_f32_16x16x32_bf16(qf[i][1], kf1[jc], s[i][jc], 0, 0, 0);

      if (t == tmax) {   // only the diagonal tile needs causal masking
        #pragma unroll
        for (int i = 0; i < 4; ++i)
          #pragma unroll
          for (int jc = 0; jc < 4; ++jc)
            #pragma unroll
            for (int r = 0; r < 4; ++r)
              if (jc*16 + fr > i*16 + fq*4 + r) s[i][jc][r] = -1e30f;
      }

      #pragma unroll
      for (int i = 0; i < 4; ++i) {
        float tm[4];
        #pragma unroll
        for (int r = 0; r < 4; ++r)
          tm[r] = fmaxf(fmaxf(s[i][0][r], s[i][1][r]), fmaxf(s[i][2][r], s[i][3][r]));
        #pragma unroll
        for (int off = 1; off < 16; off <<= 1)
          #pragma unroll
          for (int r = 0; r < 4; ++r)
            tm[r] = fmaxf(tm[r], __shfl_xor(tm[r], off));
        float al[4];
        #pragma unroll
        for (int r = 0; r < 4; ++r) {
          float mn = fmaxf(mrow[i][r], tm[r]);
          al[r] = __expf(mrow[i][r] - mn);
          mrow[i][r] = mn;
        }
        short* Pw = &Pb[wid][i & 1][0];
        float rsum[4] = {0.f, 0.f, 0.f, 0.f};
        #pragma unroll
        for (int jc = 0; jc < 4; ++jc)
          #pragma unroll
          for (int r = 0; r < 4; ++r) {
            float p = __expf(s[i][jc][r] - mrow[i][r]);
            rsum[r] += p;
            Pw[(fq*4 + r)*72 + jc*16 + fr] = f2bf(p);
          }
        #pragma unroll
        for (int dc = 0; dc < 4; ++dc)
          #pragma unroll
          for (int r = 0; r < 4; ++r)
            o[i][dc][r] *= al[r];
        asm volatile("s_waitcnt lgkmcnt(0)" ::: "memory");  // P visible cross-lane
        #pragma unroll
        for (int jk = 0; jk < 2; ++jk) {
          bf16x8 pf = *reinterpret_cast<const bf16x8*>(&Pw[fr*72 + jk*32 + fq*8]);
          #pragma unroll
          for (int dc = 0; dc < 4; ++dc)
            o[i][dc] = __builtin_amdgcn_mfma_f32_16x16x32_bf16(pf, vf[jk][dc], o[i][dc], 0, 0, 0);
        }
        #pragma unroll
        for (int off = 1; off < 16; off <<= 1)
          #pragma unroll
          for (int r = 0; r < 4; ++r)
            rsum[r] += __shfl_xor(rsum[r], off);
        #pragma unroll
        for (int r = 0; r < 4; ++r)
          lrow[i][r] = lrow[i][r]*al[r] + rsum[r];
      }
    }
    if (more) {   // write next tile into the other buffer
      *reinterpret_cast<int4v*>(&Ks[buf ^ 1][soff]) = kk;
      *reinterpret_cast<int4v*>(&Vs[buf ^ 1][soff]) = vv;
    }
    __syncthreads();
  }

  short* obase = attnb + ((size_t)(b*SEQV + w*WIDTHV + qbase))*1024 + h*64;
  #pragma unroll
  for (int i = 0; i < 4; ++i) {
    float inv[4];
    #pragma unroll
    for (int r = 0; r < 4; ++r) inv[r] = 1.0f / lrow[i][r];
    #pragma unroll
    for (int dc = 0; dc < 4; ++dc)
      #pragma unroll
      for (int r = 0; r < 4; ++r)
        __builtin_nontemporal_store(f2bf(o[i][dc][r] * inv[r]),
            &obase[(size_t)(i*16 + fq*4 + r)*1024 + dc*16 + fr]);
  }
}

// ------------------------------------------------------------------- host
extern "C" void kernel_launch(void* const* d_in, const int* in_sizes, int n_in,
                              void* d_out, int out_size, void* d_ws, size_t ws_size,
                              hipStream_t stream) {
  const float* x     = (const float*)d_in[0];
  const float* bias  = (const float*)d_in[1];
  const float* xl    = (const float*)d_in[2];
  const float* gamma = (const float*)d_in[3];
  const float* w_qkv = (const float*)d_in[4];
  const float* w_out = (const float*)d_in[5];
  float* out = (float*)d_out;
  float* mem_out = out + (size_t)BATCHV*SEQV*DIMV;   // +8388608

  char* ws = (char*)d_ws;
  size_t off = 0;
  auto alloc = [&](size_t bytes) { size_t o = off; off += (bytes + 255) & ~(size_t)255; return o; };
  short* xn    = (short*)(ws + alloc((size_t)NROWS*DIMV*2));          // aliased by attnb
  short* wqkvT = (short*)(ws + alloc((size_t)3*INNERV*DIMV*2));
  short* woutT = (short*)(ws + alloc((size_t)DIMV*INNERV*2));
  short* bp    = (short*)(ws + alloc((size_t)HEADSV*128*1024*4*2));   // packed bias
  short* qbuf  = (short*)(ws + alloc((size_t)NROWS*INNERV*2));
  short* k_all = (short*)(ws + alloc((size_t)BATCHV*HEADSV*KVROWS*DHEADV*2));
  short* v_all = (short*)(ws + alloc((size_t)BATCHV*HEADSV*KVROWS*DHEADV*2));
  short* vt    = (short*)(ws + alloc((size_t)BATCHV*HEADSV*KVROWS*DHEADV*2));
  short* attnb = xn;  // xn dead after QKV GEMM; reuse for attention output

  // weight transposes (fp32 (R,C) -> bf16 (C,R))
  transpose_f32_bf16<<<dim3(3*INNERV/32, DIMV/32), 256, 0, stream>>>(w_qkv, wqkvT, DIMV, 3*INNERV);
  transpose_f32_bf16<<<dim3(INNERV/32, DIMV/32), 256, 0, stream>>>(w_out, woutT, DIMV, INNERV);
  // bias -> fragment-packed bf16
  pack_bias<<<8192, 256, 0, stream>>>(bias, bp);
  // xl memories -> k_all/v_all prefix rows
  xl_to_kv<<<2048, 256, 0, stream>>>(xl, k_all, v_all);
  // layernorm
  ln_kernel<<<NROWS, 256, 0, stream>>>(x, gamma, xn);
  // QKV projection (+ memories fp32 epilogue; q pre-scaled by 0.125)
  gemm_bt<0><<<dim3(NROWS/128, (3*INNERV)/128), 256, 0, stream>>>(
      xn, wqkvT, qbuf, k_all, v_all, mem_out, nullptr, 3*INNERV);
  // V transpose for PV-operand reads
  transpose_v<<<dim3(KVROWS/64, BATCHV*HEADSV), 256, 0, stream>>>(v_all, vt);
  // attention
  attn_kernel<<<BATCHV*8*HEADSV, 512, 0, stream>>>(qbuf, k_all, vt, bp, attnb);
  // output projection -> fp32 d_out
  gemm_bt<1><<<dim3(NROWS/128, INNERV/128), 256, 0, stream>>>(
      attnb, woutT, nullptr, nullptr, nullptr, nullptr, out, INNERV);
}